// Round 7
// baseline (61.256 us; speedup 1.0000x reference)
//
#include <hip/hip_runtime.h>

// R7 = DIAGNOSTIC ROUND. R5 structure (best: 23.7us) + REP x4 internal repeat
// so anfis_main (~80us) outranks the harness's 39us fill dispatches in the
// rocprof top-5 and we finally see its VALUBusy / Occupancy / VGPR / LDS
// counters. dur_us will be ~4x the real kernel — intentional, one round.

#define NS 131072
#define D 16
#define R 32
#define O 10
#define KTOT 544          // R*D (affine) + R (bias block)
#define EPSF 1e-8f
#define REP 4

typedef float v2     __attribute__((ext_vector_type(2)));
typedef float f32x4  __attribute__((ext_vector_type(4)));
typedef short bf16x8 __attribute__((ext_vector_type(8)));

// f32 -> bf16 bits, round-nearest-even (prep only)
static __device__ __forceinline__ short bf(float f) {
    union { float f; unsigned u; } v; v.f = f;
    unsigned r = (v.u + 0x7fffu + ((v.u >> 16) & 1u)) >> 16;
    return (short)r;
}

// packed f32x2 -> bf16x2 in one HW instr (T12 pattern; no builtin on gfx950)
static __device__ __forceinline__ unsigned cvtpk(float lo, float hi) {
    unsigned r;
    asm("v_cvt_pk_bf16_f32 %0, %1, %2" : "=v"(r) : "v"(lo), "v"(hi));
    return r;
}

__global__ void anfis_prep(const float* __restrict__ sigmas,
                           const float* __restrict__ centers,
                           const float* __restrict__ coeffs,
                           float* __restrict__ nw,
                           float* __restrict__ nm1,
                           float* __restrict__ nc0,
                           unsigned short* __restrict__ Ct) {
    int i = blockIdx.x * blockDim.x + threadIdx.x;
    if (i < R * D) {
        float s = sigmas[i], c = centers[i];
        float w = -0.5f / (s * s);
        nw[i]  = w;
        nm1[i] = -2.0f * w * c;
    }
    if (i < R) {
        float acc = 0.f;
        for (int d = 0; d < D; ++d) {
            float s = sigmas[i * D + d], c = centers[i * D + d];
            acc += (-0.5f / (s * s)) * c * c;
        }
        nc0[i] = acc;
    }
    if (i < 16 * KTOT) {
        int o = i / KTOT, k = i % KTOT;
        float v = 0.f;
        if (o < O) {
            if (k < R * D) { int r = k >> 4, d = k & 15; v = coeffs[(r * (D + 1) + d) * O + o]; }
            else           { int r = k - R * D;          v = coeffs[(r * (D + 1) + D) * O + o]; }
        }
        Ct[i] = (unsigned short)bf(v);
    }
}

__global__ __launch_bounds__(256, 8) void anfis_main(
    const float* __restrict__ X,
    const float* __restrict__ nw,
    const float* __restrict__ nm1,
    const float* __restrict__ nc0,
    const unsigned short* __restrict__ Ct,
    float* __restrict__ out)
{
    const int tid  = threadIdx.x;
    const int lane = tid & 63;
    const int w    = __builtin_amdgcn_readfirstlane(tid >> 6);
    const int n    = blockIdx.x * 64 + lane;

    __shared__ char  lbuf[4 * 4352];
    __shared__ float sbuf[256];
    bf16x8* zw = reinterpret_cast<bf16x8*>(lbuf + w * 4352);
    float*  rw = reinterpret_cast<float*> (lbuf + w * 4352);

    // ---- load x (once; reps reuse registers) ----
    v2 x2[8];
    {
        const float4* xp = reinterpret_cast<const float4*>(X + (size_t)n * D);
        #pragma unroll
        for (int i = 0; i < 4; ++i) {
            float4 v = xp[i];
            x2[2*i]   = v2{v.x, v.y};
            x2[2*i+1] = v2{v.z, v.w};
        }
    }

    const int o = lane & 15, g = lane >> 4;
    const unsigned short* cbase = Ct + o * KTOT + g * 8;

    #pragma unroll 1
    for (int rep = 0; rep < REP; ++rep) {

        bf16x8 bnext = *reinterpret_cast<const bf16x8*>(cbase + w * 128);

        // ---- membership: e = sum_d (w x^2 + m1 x) + c0 ----
        float s[8];
        float psum = 0.f;
        {
            v2 xsq[8];
            #pragma unroll
            for (int i = 0; i < 8; ++i) xsq[i] = x2[i] * x2[i];
            const int r0 = w * 8;
            #pragma unroll
            for (int j = 0; j < 8; ++j) {
                const int r = r0 + j;
                const v2* W2 = reinterpret_cast<const v2*>(nw  + r * D);
                const v2* M2 = reinterpret_cast<const v2*>(nm1 + r * D);
                v2 e2 = v2{0.f, 0.f};
                #pragma unroll
                for (int i = 0; i < 8; ++i) {
                    e2 = __builtin_elementwise_fma(xsq[i], W2[i], e2);
                    e2 = __builtin_elementwise_fma(x2[i],  M2[i], e2);
                }
                s[j] = __expf(e2.x + e2.y + nc0[r]);
                psum += s[j];
            }
        }

        // ---- cross-wave ssum; lane-local normalized strengths ----
        sbuf[tid] = psum;
        __syncthreads();
        float tot = sbuf[lane] + sbuf[lane + 64] + sbuf[lane + 128] + sbuf[lane + 192];
        const float inv = __builtin_amdgcn_rcpf(tot + EPSF);
        float nrm[8];
        #pragma unroll
        for (int j = 0; j < 8; ++j) nrm[j] = s[j] * inv;

        f32x4 acc[4];
        #pragma unroll
        for (int rt = 0; rt < 4; ++rt) acc[rt] = f32x4{0.f, 0.f, 0.f, 0.f};

        #define ZPHYS(row, chunk) ((((row) * 4 + (chunk)) ^ (((row) >> 1) & 7)))

        // ---- 5 phases: p<4 => 2 rules (K=32); p==4 => bias block ----
        #pragma unroll
        for (int p = 0; p < 5; ++p) {
            bf16x8 bcur = bnext;
            if (p < 4) {
                const int k0n = (p + 1 < 4) ? (w * 128 + (p + 1) * 32) : (R * D);
                bnext = *reinterpret_cast<const bf16x8*>(cbase + k0n);
            }
            if (p < 4) {
                #pragma unroll
                for (int j = 0; j < 4; ++j) {
                    const float nq = nrm[2 * p + (j >> 1)];
                    union { unsigned u[4]; bf16x8 v; } ch;
                    #pragma unroll
                    for (int m = 0; m < 4; ++m) {
                        v2 t = x2[(j & 1) * 4 + m] * nq;
                        ch.u[m] = cvtpk(t.x, t.y);
                    }
                    zw[ZPHYS(lane, j)] = ch.v;
                }
            } else {
                #pragma unroll
                for (int j = 0; j < 4; ++j) {
                    union { unsigned u[4]; bf16x8 v; } ch;
                    #pragma unroll
                    for (int m = 0; m < 4; ++m)
                        ch.u[m] = (j == w) ? cvtpk(nrm[2 * m], nrm[2 * m + 1]) : 0u;
                    zw[ZPHYS(lane, j)] = ch.v;
                }
            }
            #pragma unroll
            for (int rt = 0; rt < 4; ++rt) {
                bf16x8 af = zw[ZPHYS((lane & 15) + rt * 16, g)];
                acc[rt] = __builtin_amdgcn_mfma_f32_16x16x32_bf16(af, bcur, acc[rt], 0, 0, 0);
            }
        }

        // ---- stash C-partials over the Z region (wave-private) ----
        #pragma unroll
        for (int rt = 0; rt < 4; ++rt) {
            #pragma unroll
            for (int j = 0; j < 4; ++j)
                rw[(rt * 16 + g * 4 + j) * 17 + o] = acc[rt][j];
        }
        __syncthreads();

        // ---- epilogue: wave 0, lane = sample ----
        if (tid < 64) {
            float a[O];
            #pragma unroll
            for (int oo = 0; oo < O; ++oo) {
                a[oo] = reinterpret_cast<const float*>(lbuf +    0)[tid * 17 + oo]
                      + reinterpret_cast<const float*>(lbuf + 4352)[tid * 17 + oo]
                      + reinterpret_cast<const float*>(lbuf + 8704)[tid * 17 + oo]
                      + reinterpret_cast<const float*>(lbuf +13056)[tid * 17 + oo];
            }
            float m = a[0];
            #pragma unroll
            for (int oo = 1; oo < O; ++oo) m = fmaxf(m, a[oo]);
            float e_[O]; float se = 0.f;
            #pragma unroll
            for (int oo = 0; oo < O; ++oo) { e_[oo] = __expf(a[oo] - m); se += e_[oo]; }
            const float rs = __builtin_amdgcn_rcpf(se);
            float2* op = reinterpret_cast<float2*>(out + (size_t)(blockIdx.x * 64 + tid) * O);
            #pragma unroll
            for (int pp = 0; pp < 5; ++pp) op[pp] = make_float2(e_[2*pp] * rs, e_[2*pp+1] * rs);
        }
        __syncthreads();   // protect lbuf WAR before next rep
    }
}

extern "C" void kernel_launch(void* const* d_in, const int* in_sizes, int n_in,
                              void* d_out, int out_size, void* d_ws, size_t ws_size,
                              hipStream_t stream) {
    const float* X       = (const float*)d_in[0];
    const float* centers = (const float*)d_in[1];
    const float* sigmas  = (const float*)d_in[2];
    const float* coeffs  = (const float*)d_in[3];
    float* out = (float*)d_out;

    float* nw  = (float*)d_ws;                                   // 512 f32 @ 0
    float* nm1 = (float*)((char*)d_ws + 2048);                   // 512 f32
    float* nc0 = (float*)((char*)d_ws + 4096);                   // 32 f32
    unsigned short* Ct = (unsigned short*)((char*)d_ws + 4224);  // 16*544 bf16

    anfis_prep<<<(16 * KTOT + 255) / 256, 256, 0, stream>>>(sigmas, centers, coeffs,
                                                            nw, nm1, nc0, Ct);
    anfis_main<<<NS / 64, 256, 0, stream>>>(X, nw, nm1, nc0, Ct, out);
}

// Round 8
// 40.191 us; speedup vs baseline: 1.5241x; 1.5241x over previous
//
#include <hip/hip_runtime.h>

#define NS 131072
#define D 16
#define R 32
#define O 10
#define EPSF 1e-8f

#define KC 544           // consequent K: 16 phases (d=p) * 32 + 32 bias
#define KM 128           // membership K: hi/lo expansion, 4 phases of 32

typedef float v2     __attribute__((ext_vector_type(2)));
typedef float f32x4  __attribute__((ext_vector_type(4)));
typedef short bf16x8 __attribute__((ext_vector_type(8)));

// packed f32x2 -> bf16x2, one HW instr; low16 = first arg (verified R4/R5 pass)
static __device__ __forceinline__ unsigned cvtpk(float lo, float hi) {
    unsigned r;
    asm("v_cvt_pk_bf16_f32 %0, %1, %2" : "=v"(r) : "v"(lo), "v"(hi));
    return r;
}
static __device__ __forceinline__ unsigned short bfh(float f) {
    union { float f; unsigned u; } v; v.f = f;
    return (unsigned short)((v.u + 0x7fffu + ((v.u >> 16) & 1u)) >> 16);
}
static __device__ __forceinline__ float bf2f(unsigned short h) {
    union { unsigned u; float f; } v; v.u = ((unsigned)h) << 16;
    return v.f;
}

// ---------------- prep: build the two A-tables ----------------
// Amem[grp][rr][k] (2x16x128 bf16): rule r = grp*16+rr,
//   k[0,16): whi[d]   (pairs B=X2hi)     k[16,32): whi[d]  (pairs X2lo)
//   k[32,48): wlo[d]  (pairs X2hi)       k[48,64): m1hi[d] (pairs xhi)
//   k[64,80): m1hi[d] (pairs xlo)        k[80,96): m1lo[d] (pairs xhi)
//   k=96: c0hi  k=97: c0lo (pair B=1)    k[98,128): 0
//   where w=-1/(2s^2), m1=c/s^2, c0=sum_d w*c^2, hi/lo = bf16 split.
// Acons[o][k] (16x544 bf16): k<512: p=k>>5, g=(k&31)>>3, e=k&7:
//   rule = 4g+16(e>>2)+(e&3), d = p;  k>=512: same rule formula, d = bias.
__global__ void anfis_prep(const float* __restrict__ sigmas,
                           const float* __restrict__ centers,
                           const float* __restrict__ coeffs,
                           unsigned short* __restrict__ Amem,
                           unsigned short* __restrict__ Acons) {
    int i = blockIdx.x * blockDim.x + threadIdx.x;
    if (i < 2 * 16 * KM) {
        int rr = (i >> 7) & 15;
        int r  = (i >> 11) * 16 + rr;
        int k  = i & 127;
        unsigned short outv = 0;
        if (k < 96) {
            int d = k & 15;
            float s = sigmas[r * D + d], c = centers[r * D + d];
            float w  = -0.5f / (s * s);
            float m1 = -2.f * w * c;
            int seg = k >> 4;                        // 0..5
            float base = (seg < 3) ? w : m1;
            unsigned short hi = bfh(base);
            bool wantlo = (seg == 2) || (seg == 5);
            outv = wantlo ? bfh(base - bf2f(hi)) : hi;
        } else if (k == 96 || k == 97) {
            float c0 = 0.f;
            for (int d = 0; d < D; ++d) {
                float s = sigmas[r * D + d], c = centers[r * D + d];
                c0 += (-0.5f / (s * s)) * c * c;
            }
            unsigned short hi = bfh(c0);
            outv = (k == 97) ? bfh(c0 - bf2f(hi)) : hi;
        }
        Amem[i] = outv;
        return;
    }
    int j = i - 2 * 16 * KM;
    if (j < 16 * KC) {
        int o = j / KC, k = j % KC;
        unsigned short val = 0;
        if (o < O) {
            int t = (k < 512) ? (k & 31) : (k - 512);
            int g = t >> 3, e = t & 7;
            int rч = 4 * g + 16 * (e >> 2) + (e & 3);
            int d = (k < 512) ? (k >> 5) : D;
            val = bfh(coeffs[(rч * (D + 1) + d) * O + o]);
        }
        Acons[j] = val;
    }
}

// ---------------- main: no LDS, no barriers, no spills ----------------
// Wave = 16 samples. lane = 16g + c: sample c, k-slice g.
// Membership GEMM (rules x samples) then consequent GEMM (o x samples),
// both with lane-local register B-fragments. Softmax via 4-lane shfl_xor.
__global__ __launch_bounds__(256, 4) void anfis_main(
    const float* __restrict__ X,
    const unsigned short* __restrict__ Amem,
    const unsigned short* __restrict__ Acons,
    float* __restrict__ out)
{
    const int tid  = threadIdx.x;
    const int lane = tid & 63;
    const int wv   = tid >> 6;
    const int c    = lane & 15;
    const int g    = lane >> 4;
    const int n    = blockIdx.x * 64 + wv * 16 + c;

    // ---- load all 16 features of this lane's sample ----
    float x[16];
    {
        const float4* xp = reinterpret_cast<const float4*>(X + (size_t)n * D);
        #pragma unroll
        for (int i = 0; i < 4; ++i) {
            float4 v = xp[i];
            x[4*i] = v.x; x[4*i+1] = v.y; x[4*i+2] = v.z; x[4*i+3] = v.w;
        }
    }

    const bool hsel = (g & 1);        // d-half of this k-slice
    const bool qsel = (lane >= 32);   // q = g>>1: 0 -> {X2hi,xlo}, 1 -> {X2lo,xhi}

    float xh[8], x2h[8];
    #pragma unroll
    for (int i = 0; i < 8; ++i) xh[i] = hsel ? x[8 + i] : x[i];
    #pragma unroll
    for (int i = 0; i < 8; ++i) x2h[i] = xh[i] * xh[i];

    // ---- membership B-fragments (in-register, per-lane) ----
    union U4 { unsigned u[4]; bf16x8 v; };
    U4 Fa, Fb, Fc, Bp1;
    if (!qsel) {
        #pragma unroll
        for (int i = 0; i < 4; ++i) Fa.u[i] = cvtpk(x2h[2*i], x2h[2*i+1]);     // X2hi
        #pragma unroll
        for (int i = 0; i < 4; ++i) {                                           // xlo
            unsigned hi = cvtpk(xh[2*i], xh[2*i+1]);
            float ah = __uint_as_float(hi << 16);
            float bh = __uint_as_float(hi & 0xFFFF0000u);
            Fb.u[i] = cvtpk(xh[2*i] - ah, xh[2*i+1] - bh);
        }
    } else {
        #pragma unroll
        for (int i = 0; i < 4; ++i) {                                           // X2lo
            unsigned hi = cvtpk(x2h[2*i], x2h[2*i+1]);
            float ah = __uint_as_float(hi << 16);
            float bh = __uint_as_float(hi & 0xFFFF0000u);
            Fa.u[i] = cvtpk(x2h[2*i] - ah, x2h[2*i+1] - bh);
        }
        #pragma unroll
        for (int i = 0; i < 4; ++i) Fb.u[i] = cvtpk(xh[2*i], xh[2*i+1]);       // xhi
    }
    Fc.u[0] = 0x3F803F80u; Fc.u[1] = 0; Fc.u[2] = 0; Fc.u[3] = 0;              // (1,1,0..)
    #pragma unroll
    for (int i = 0; i < 4; ++i) Bp1.u[i] = qsel ? Fb.u[i] : Fa.u[i];

    // ---- membership MFMA: e[rule][sample], 2 rule-groups x 4 K-steps ----
    const unsigned short* am = Amem + c * KM + g * 8;
    f32x4 em0 = {0.f,0.f,0.f,0.f}, em1 = {0.f,0.f,0.f,0.f};
    {
        bf16x8 a0 = *(const bf16x8*)(am);
        bf16x8 a1 = *(const bf16x8*)(am + 32);
        bf16x8 a2 = *(const bf16x8*)(am + 64);
        bf16x8 a3 = *(const bf16x8*)(am + 96);
        em0 = __builtin_amdgcn_mfma_f32_16x16x32_bf16(a0, Fa.v,  em0, 0, 0, 0);
        em0 = __builtin_amdgcn_mfma_f32_16x16x32_bf16(a1, Bp1.v, em0, 0, 0, 0);
        em0 = __builtin_amdgcn_mfma_f32_16x16x32_bf16(a2, Fb.v,  em0, 0, 0, 0);
        em0 = __builtin_amdgcn_mfma_f32_16x16x32_bf16(a3, Fc.v,  em0, 0, 0, 0);
        const unsigned short* ag = am + 16 * KM;
        bf16x8 b0 = *(const bf16x8*)(ag);
        bf16x8 b1 = *(const bf16x8*)(ag + 32);
        bf16x8 b2 = *(const bf16x8*)(ag + 64);
        bf16x8 b3 = *(const bf16x8*)(ag + 96);
        em1 = __builtin_amdgcn_mfma_f32_16x16x32_bf16(b0, Fa.v,  em1, 0, 0, 0);
        em1 = __builtin_amdgcn_mfma_f32_16x16x32_bf16(b1, Bp1.v, em1, 0, 0, 0);
        em1 = __builtin_amdgcn_mfma_f32_16x16x32_bf16(b2, Fb.v,  em1, 0, 0, 0);
        em1 = __builtin_amdgcn_mfma_f32_16x16x32_bf16(b3, Fc.v,  em1, 0, 0, 0);
    }

    // ---- s = exp(e); group-total via shfl; keep UNNORMALIZED (defer inv) ----
    float s0 = __expf(em0[0]), s1 = __expf(em0[1]), s2 = __expf(em0[2]), s3 = __expf(em0[3]);
    float s4 = __expf(em1[0]), s5 = __expf(em1[1]), s6 = __expf(em1[2]), s7 = __expf(em1[3]);
    float psum = ((s0 + s1) + (s2 + s3)) + ((s4 + s5) + (s6 + s7));
    float t1  = psum + __shfl_xor(psum, 16);
    float tot = t1 + __shfl_xor(t1, 32);
    const float inv = __builtin_amdgcn_rcpf(tot + EPSF);
    v2 sp[4] = { v2{s0, s1}, v2{s2, s3}, v2{s4, s5}, v2{s6, s7} };

    // ---- consequent: 17 K-steps, B[e] = s[e] * x[p] (p=16: bias, B=s) ----
    const unsigned short* ac = Acons + c * KC + g * 8;
    f32x4 aA = {0.f,0.f,0.f,0.f}, aB = {0.f,0.f,0.f,0.f};
    bf16x8 an = *(const bf16x8*)(ac);
    #pragma unroll
    for (int p = 0; p <= 16; ++p) {
        bf16x8 acur = an;
        if (p < 16) an = *(const bf16x8*)(ac + 32 * (p + 1));
        U4 B;
        if (p < 16) {
            const float xp = x[p];
            #pragma unroll
            for (int i = 0; i < 4; ++i) { v2 t = sp[i] * xp; B.u[i] = cvtpk(t.x, t.y); }
        } else {
            #pragma unroll
            for (int i = 0; i < 4; ++i) B.u[i] = cvtpk(sp[i].x, sp[i].y);
        }
        if (p & 1) aB = __builtin_amdgcn_mfma_f32_16x16x32_bf16(acur, B.v, aB, 0, 0, 0);
        else       aA = __builtin_amdgcn_mfma_f32_16x16x32_bf16(acur, B.v, aA, 0, 0, 0);
    }

    // ---- epilogue: normalize, masked softmax over the 4-lane group, store ----
    const int obase = g * 4;
    float a0 = (aA[0] + aB[0]) * inv;
    float a1 = (aA[1] + aB[1]) * inv;
    float a2 = (aA[2] + aB[2]) * inv;
    float a3 = (aA[3] + aB[3]) * inv;
    float av0 = (obase + 0 < O) ? a0 : -1e30f;
    float av1 = (obase + 1 < O) ? a1 : -1e30f;
    float av2 = (obase + 2 < O) ? a2 : -1e30f;
    float av3 = (obase + 3 < O) ? a3 : -1e30f;
    float m = fmaxf(fmaxf(av0, av1), fmaxf(av2, av3));
    m = fmaxf(m, __shfl_xor(m, 16));
    m = fmaxf(m, __shfl_xor(m, 32));
    float e0 = __expf(av0 - m), e1 = __expf(av1 - m);
    float e2 = __expf(av2 - m), e3 = __expf(av3 - m);
    float ss = (e0 + e1) + (e2 + e3);
    float u1 = ss + __shfl_xor(ss, 16);
    float st = u1 + __shfl_xor(u1, 32);
    const float rs = __builtin_amdgcn_rcpf(st);

    float* op = out + (size_t)n * O + obase;
    if (g < 2) {
        *reinterpret_cast<float2*>(op)     = make_float2(e0 * rs, e1 * rs);
        *reinterpret_cast<float2*>(op + 2) = make_float2(e2 * rs, e3 * rs);
    } else if (g == 2) {
        *reinterpret_cast<float2*>(op)     = make_float2(e0 * rs, e1 * rs);
    }
}

extern "C" void kernel_launch(void* const* d_in, const int* in_sizes, int n_in,
                              void* d_out, int out_size, void* d_ws, size_t ws_size,
                              hipStream_t stream) {
    const float* X       = (const float*)d_in[0];
    const float* centers = (const float*)d_in[1];
    const float* sigmas  = (const float*)d_in[2];
    const float* coeffs  = (const float*)d_in[3];
    float* out = (float*)d_out;

    unsigned short* Amem  = (unsigned short*)d_ws;                    // 4096 bf16 = 8 KB
    unsigned short* Acons = (unsigned short*)((char*)d_ws + 8192);    // 8704 bf16 = 17 KB

    const int prep_elems = 2 * 16 * KM + 16 * KC;                     // 12800
    anfis_prep<<<(prep_elems + 255) / 256, 256, 0, stream>>>(sigmas, centers, coeffs,
                                                             Amem, Acons);
    anfis_main<<<NS / 64, 256, 0, stream>>>(X, Amem, Acons, out);
}

// Round 9
// 21.560 us; speedup vs baseline: 2.8412x; 1.8642x over previous
//
#include <hip/hip_runtime.h>

#define NS 131072
#define D 16
#define R 32
#define O 10
#define KTOT 544          // R*D (affine) + R (bias block)
#define EPSF 1e-8f

typedef float v2     __attribute__((ext_vector_type(2)));
typedef float f32x4  __attribute__((ext_vector_type(4)));
typedef short bf16x8 __attribute__((ext_vector_type(8)));

// f32 -> bf16 bits, round-nearest-even (prep only)
static __device__ __forceinline__ short bf(float f) {
    union { float f; unsigned u; } v; v.f = f;
    unsigned r = (v.u + 0x7fffu + ((v.u >> 16) & 1u)) >> 16;
    return (short)r;
}

// packed f32x2 -> bf16x2 in one HW instr
static __device__ __forceinline__ unsigned cvtpk(float lo, float hi) {
    unsigned r;
    asm("v_cvt_pk_bf16_f32 %0, %1, %2" : "=v"(r) : "v"(lo), "v"(hi));
    return r;
}

// prep: nw=-1/(2s^2), nm1=c/s^2, nc0[r]=sum_d w c^2, Ct[o][k] bf16 (16 x 544)
__global__ void anfis_prep(const float* __restrict__ sigmas,
                           const float* __restrict__ centers,
                           const float* __restrict__ coeffs,
                           float* __restrict__ nw,
                           float* __restrict__ nm1,
                           float* __restrict__ nc0,
                           unsigned short* __restrict__ Ct) {
    int i = blockIdx.x * blockDim.x + threadIdx.x;
    if (i < R * D) {
        float s = sigmas[i], c = centers[i];
        float w = -0.5f / (s * s);
        nw[i]  = w;
        nm1[i] = -2.0f * w * c;
    }
    if (i < R) {
        float acc = 0.f;
        for (int d = 0; d < D; ++d) {
            float s = sigmas[i * D + d], c = centers[i * D + d];
            acc += (-0.5f / (s * s)) * c * c;
        }
        nc0[i] = acc;
    }
    if (i < 16 * KTOT) {
        int o = i / KTOT, k = i % KTOT;
        float v = 0.f;
        if (o < O) {
            if (k < R * D) { int r = k >> 4, d = k & 15; v = coeffs[(r * (D + 1) + d) * O + o]; }
            else           { int r = k - R * D;          v = coeffs[(r * (D + 1) + D) * O + o]; }
        }
        Ct[i] = (unsigned short)bf(v);
    }
}

// R5 skeleton, register-dieted: 4 waves x 64 samples, wave w owns rules
// [8w,8w+8); membership on VALU (expanded form), consequent via 5 MFMA
// phases on Z = nrm*x staged in wave-private swizzled LDS.
// launch_bounds(256,4): 128-VGPR budget vs ~70 live -> provably spill-free.
__global__ __launch_bounds__(256, 4) void anfis_main(
    const float* __restrict__ X,
    const float* __restrict__ nw,
    const float* __restrict__ nm1,
    const float* __restrict__ nc0,
    const unsigned short* __restrict__ Ct,
    float* __restrict__ out)
{
    const int tid  = threadIdx.x;
    const int lane = tid & 63;
    const int w    = __builtin_amdgcn_readfirstlane(tid >> 6);
    const int n    = blockIdx.x * 64 + lane;

    // per-wave 4352B region: Z (64 x 4 x 16B) then C-partials (64 x 17 f32) overlaid
    __shared__ char  lbuf[4 * 4352];
    __shared__ float sbuf[256];
    bf16x8* zw = reinterpret_cast<bf16x8*>(lbuf + w * 4352);
    float*  rw = reinterpret_cast<float*> (lbuf + w * 4352);

    // ---- load x ----
    v2 x2[8];
    {
        const float4* xp = reinterpret_cast<const float4*>(X + (size_t)n * D);
        #pragma unroll
        for (int i = 0; i < 4; ++i) {
            float4 v = xp[i];
            x2[2*i]   = v2{v.x, v.y};
            x2[2*i+1] = v2{v.z, v.w};
        }
    }

    // ---- B prefetch for phase 0 ----
    const int o = lane & 15, g = lane >> 4;
    const unsigned short* cbase = Ct + o * KTOT + g * 8;
    bf16x8 bnext = *reinterpret_cast<const bf16x8*>(cbase + w * 128);

    // ---- membership: e = sum_d (w x^2 + m1 x) + c0 ----
    float s[8];
    {
        const int r0 = w * 8;
        float psum = 0.f;
        #pragma unroll
        for (int j = 0; j < 8; ++j) {
            const int r = r0 + j;
            const v2* W2 = reinterpret_cast<const v2*>(nw  + r * D);
            const v2* M2 = reinterpret_cast<const v2*>(nm1 + r * D);
            v2 e2 = v2{0.f, 0.f};
            #pragma unroll
            for (int i = 0; i < 8; ++i) {
                e2 = __builtin_elementwise_fma(x2[i] * x2[i], W2[i], e2);
                e2 = __builtin_elementwise_fma(x2[i],         M2[i], e2);
            }
            s[j] = __expf(e2.x + e2.y + nc0[r]);
            psum += s[j];
        }
        sbuf[tid] = psum;
    }
    __syncthreads();

    // ---- normalize strengths IN PLACE (no nrm[] array) ----
    {
        float tot = sbuf[lane] + sbuf[lane + 64] + sbuf[lane + 128] + sbuf[lane + 192];
        const float inv = __builtin_amdgcn_rcpf(tot + EPSF);
        #pragma unroll
        for (int j = 0; j < 8; ++j) s[j] *= inv;
    }

    f32x4 acc[4];
    #pragma unroll
    for (int rt = 0; rt < 4; ++rt) acc[rt] = f32x4{0.f, 0.f, 0.f, 0.f};

    #define ZPHYS(row, chunk) ((((row) * 4 + (chunk)) ^ (((row) >> 1) & 7)))

    // ---- 5 phases: p<4 => 2 rules (K=32); p==4 => bias block ----
    #pragma unroll
    for (int p = 0; p < 5; ++p) {
        bf16x8 bcur = bnext;
        if (p < 4) {
            const int k0n = (p + 1 < 4) ? (w * 128 + (p + 1) * 32) : (R * D);
            bnext = *reinterpret_cast<const bf16x8*>(cbase + k0n);
        }
        if (p < 4) {
            // z[k=q*16+d] = s[2p+q]*x[d]; chunk j: rule q=j>>1, d-range (j&1)*8..+8
            #pragma unroll
            for (int j = 0; j < 4; ++j) {
                const float nq = s[2 * p + (j >> 1)];
                union { unsigned u[4]; bf16x8 v; } ch;
                #pragma unroll
                for (int m = 0; m < 4; ++m) {
                    v2 t = x2[(j & 1) * 4 + m] * nq;
                    ch.u[m] = cvtpk(t.x, t.y);
                }
                zw[ZPHYS(lane, j)] = ch.v;
            }
        } else {
            // bias: k-slot g*8+e <-> rule g*8+e; this wave supplies chunk w only
            #pragma unroll
            for (int j = 0; j < 4; ++j) {
                union { unsigned u[4]; bf16x8 v; } ch;
                #pragma unroll
                for (int m = 0; m < 4; ++m)
                    ch.u[m] = (j == w) ? cvtpk(s[2 * m], s[2 * m + 1]) : 0u;
                zw[ZPHYS(lane, j)] = ch.v;
            }
        }
        #pragma unroll
        for (int rt = 0; rt < 4; ++rt) {
            bf16x8 af = zw[ZPHYS((lane & 15) + rt * 16, g)];
            acc[rt] = __builtin_amdgcn_mfma_f32_16x16x32_bf16(af, bcur, acc[rt], 0, 0, 0);
        }
    }

    // ---- stash C-partials over the Z region (wave-private) ----
    #pragma unroll
    for (int rt = 0; rt < 4; ++rt) {
        #pragma unroll
        for (int j = 0; j < 4; ++j)
            rw[(rt * 16 + g * 4 + j) * 17 + o] = acc[rt][j];
    }
    __syncthreads();

    // ---- epilogue: wave 0, lane = sample ----
    if (tid < 64) {
        float a[O];
        #pragma unroll
        for (int oo = 0; oo < O; ++oo) {
            a[oo] = reinterpret_cast<const float*>(lbuf +    0)[tid * 17 + oo]
                  + reinterpret_cast<const float*>(lbuf + 4352)[tid * 17 + oo]
                  + reinterpret_cast<const float*>(lbuf + 8704)[tid * 17 + oo]
                  + reinterpret_cast<const float*>(lbuf +13056)[tid * 17 + oo];
        }
        float m = a[0];
        #pragma unroll
        for (int oo = 1; oo < O; ++oo) m = fmaxf(m, a[oo]);
        float e_[O]; float se = 0.f;
        #pragma unroll
        for (int oo = 0; oo < O; ++oo) { e_[oo] = __expf(a[oo] - m); se += e_[oo]; }
        const float rs = __builtin_amdgcn_rcpf(se);
        float2* op = reinterpret_cast<float2*>(out + (size_t)(blockIdx.x * 64 + tid) * O);
        #pragma unroll
        for (int pp = 0; pp < 5; ++pp) op[pp] = make_float2(e_[2*pp] * rs, e_[2*pp+1] * rs);
    }
}

extern "C" void kernel_launch(void* const* d_in, const int* in_sizes, int n_in,
                              void* d_out, int out_size, void* d_ws, size_t ws_size,
                              hipStream_t stream) {
    const float* X       = (const float*)d_in[0];
    const float* centers = (const float*)d_in[1];
    const float* sigmas  = (const float*)d_in[2];
    const float* coeffs  = (const float*)d_in[3];
    float* out = (float*)d_out;

    float* nw  = (float*)d_ws;                                   // 512 f32 @ 0
    float* nm1 = (float*)((char*)d_ws + 2048);                   // 512 f32
    float* nc0 = (float*)((char*)d_ws + 4096);                   // 32 f32
    unsigned short* Ct = (unsigned short*)((char*)d_ws + 4224);  // 16*544 bf16

    anfis_prep<<<(16 * KTOT + 255) / 256, 256, 0, stream>>>(sigmas, centers, coeffs,
                                                            nw, nm1, nc0, Ct);
    anfis_main<<<NS / 64, 256, 0, stream>>>(X, nw, nm1, nc0, Ct, out);
}